// Round 1
// baseline (239.348 us; speedup 1.0000x reference)
//
#include <hip/hip_runtime.h>
#include <hip/hip_bf16.h>

// Problem constants (from reference): B=64, T=4096, Feat=32, Ch=16
// kernel (3,32,1,16), Hp = 16-3+1 = 14, Wp = 32-32+1 = 1, F=16.
// out[b,t,hp,f] = relu( (conv(b,t,hp,f) + bias[f]) * sc[t] + sh[t] )
// conv(b,t,hp,f) = sum_{i<3, j<32} x[b,t,j,hp+i] * k[i,j,0,f]
// sc[t] = gamma[t] * rsqrt(var[t]+1e-3), sh[t] = beta[t] - mean[t]*sc[t]

#define GBT 16          // bt pairs per block
#define XPAD 4          // LDS row padding (floats) -> bank-decorrelated bt rows
#define XROW (512 + XPAD)

__global__ __launch_bounds__(256) void tccnn_fused(
    const float* __restrict__ x,      // (B*T, 32, 16) flat
    const float* __restrict__ kern,   // (3,32,1,16) flat = 1536
    const float* __restrict__ bias,   // (16,)
    const float* __restrict__ gamma,  // (4096,)
    const float* __restrict__ beta,   // (4096,)
    const float* __restrict__ mmean,  // (4096,)
    const float* __restrict__ mvar,   // (4096,)
    float* __restrict__ out)          // (B*T, 14, 16) flat
{
    __shared__ float xs[GBT * XROW];      // 16 * 516 * 4B = 33024 B
    __shared__ float ws[3 * 32 * 16];     // 6144 B
    __shared__ float bs[16];

    const int tid = threadIdx.x;
    const long bt_base = (long)blockIdx.x * GBT;

    // --- stage weights (1536 floats) ---
    #pragma unroll
    for (int v = 0; v < 6; ++v) {
        int idx = v * 256 + tid;
        ws[idx] = kern[idx];
    }
    if (tid < 16) bs[tid] = bias[tid];

    // --- stage x: 16 bt * 512 floats, fully contiguous = 8192 floats ---
    // 2048 float4 loads, 8 per thread, perfectly coalesced.
    const float4* xg = (const float4*)(x + bt_base * 512);
    #pragma unroll
    for (int v = 0; v < 8; ++v) {
        int idx = v * 256 + tid;          // 0..2047
        int btl = idx >> 7;               // which bt (128 float4 per bt)
        int off = (idx & 127) << 2;       // float offset within bt
        float4 val = xg[idx];
        *(float4*)&xs[btl * XROW + off] = val;
    }
    __syncthreads();

    const int f   = tid & 15;
    const int btl = tid >> 4;
    const long bt = bt_base + btl;
    const int t  = (int)(bt & 4095);      // T = 4096

    // BN inference params folded (per-t scalars, 16 lanes share t)
    const float sc = gamma[t] * rsqrtf(mvar[t] + 1e-3f);
    const float sh = beta[t] - mmean[t] * sc;

    float acc[14];
    #pragma unroll
    for (int h = 0; h < 14; ++h) acc[h] = 0.f;

    const float* xrow = &xs[btl * XROW];
    for (int j = 0; j < 32; ++j) {
        float xr[16];
        #pragma unroll
        for (int q = 0; q < 4; ++q) {
            float4 v = *(const float4*)&xrow[j * 16 + q * 4];
            xr[q * 4 + 0] = v.x; xr[q * 4 + 1] = v.y;
            xr[q * 4 + 2] = v.z; xr[q * 4 + 3] = v.w;
        }
        #pragma unroll
        for (int i = 0; i < 3; ++i) {
            float w = ws[(i * 32 + j) * 16 + f];
            #pragma unroll
            for (int h = 0; h < 14; ++h)
                acc[h] = fmaf(xr[h + i], w, acc[h]);
        }
    }

    const float bsf = bs[f];
    float* obase = out + bt * 224;        // (14,16) per bt
    #pragma unroll
    for (int h = 0; h < 14; ++h) {
        float y = (acc[h] + bsf) * sc + sh;
        obase[h * 16 + f] = fmaxf(y, 0.f);
    }
}

extern "C" void kernel_launch(void* const* d_in, const int* in_sizes, int n_in,
                              void* d_out, int out_size, void* d_ws, size_t ws_size,
                              hipStream_t stream) {
    const float* x     = (const float*)d_in[0];
    const float* kern  = (const float*)d_in[1];
    const float* bias  = (const float*)d_in[2];
    const float* gamma = (const float*)d_in[3];
    const float* beta  = (const float*)d_in[4];
    const float* mmean = (const float*)d_in[5];
    const float* mvar  = (const float*)d_in[6];
    float* out = (float*)d_out;

    const int n_bt = 64 * 4096;               // 262144
    const int blocks = n_bt / GBT;            // 16384
    tccnn_fused<<<blocks, 256, 0, stream>>>(x, kern, bias, gamma, beta,
                                            mmean, mvar, out);
}

// Round 2
// 198.926 us; speedup vs baseline: 1.2032x; 1.2032x over previous
//
#include <hip/hip_runtime.h>
#include <hip/hip_bf16.h>

// B=64, T=4096, Feat=32, Ch=16; kernel (3,32,1,16), Hp=14, Wp=1, F=16.
// out[bt,hp,f] = relu((sum_{i<3,j<32} x[bt,j,hp+i]*k[i,j,f] + bias[f])*sc[t] + sh[t])
// sc[t] = gamma[t]*rsqrt(var[t]+1e-3), sh[t] = beta[t]-mean[t]*sc[t], t = bt % 4096
//
// R1: thread = (bt, f-group-of-4). 56 acc regs/thread. LDS reads amortized 4x
// vs R0 (which was LDS-pipe bound at ~225us by the 16-way f broadcast).

#define NBT 32              // bt pairs per block
#define XROW 516            // 512 + 4 pad floats: btl rows offset by 4 banks

__global__ __launch_bounds__(128) void tccnn_fused(
    const float* __restrict__ x,      // (B*T, 32, 16) flat
    const float* __restrict__ kern,   // (3,32,1,16) flat = 1536
    const float* __restrict__ bias,   // (16,)
    const float* __restrict__ gamma,  // (4096,)
    const float* __restrict__ beta,   // (4096,)
    const float* __restrict__ mmean,  // (4096,)
    const float* __restrict__ mvar,   // (4096,)
    float* __restrict__ out)          // (B*T, 14, 16) flat
{
    __shared__ float xs[NBT * XROW];      // 32*516*4 = 66048 B
    __shared__ float ws[3 * 32 * 16];     // 6144 B
    __shared__ float bs[16];

    const int tid = threadIdx.x;
    const long bt_base = (long)blockIdx.x * NBT;

    // --- stage weights: 1536 floats / 128 threads = 12 each ---
    #pragma unroll
    for (int v = 0; v < 12; ++v) {
        int idx = v * 128 + tid;
        ws[idx] = kern[idx];
    }
    if (tid < 16) bs[tid] = bias[tid];

    // --- stage x: 32 bt * 512 floats = 4096 float4, coalesced ---
    const float4* xg = (const float4*)(x + bt_base * 512);
    #pragma unroll
    for (int v = 0; v < 32; ++v) {
        int idx = v * 128 + tid;          // 0..4095
        int btl = idx >> 7;               // 128 float4 per bt
        int off = (idx & 127) << 2;       // float offset within bt row
        *(float4*)&xs[btl * XROW + off] = xg[idx];
    }
    __syncthreads();

    const int fg  = tid & 3;              // f-group: f = fg*4 .. fg*4+3
    const int btl = tid >> 2;             // 0..31
    const long bt = bt_base + btl;
    const int t  = (int)(bt & 4095);      // T = 4096

    const float sc = gamma[t] * rsqrtf(mvar[t] + 1e-3f);
    const float sh = beta[t] - mmean[t] * sc;

    float4 acc[14];
    #pragma unroll
    for (int h = 0; h < 14; ++h) acc[h] = make_float4(0.f, 0.f, 0.f, 0.f);

    const float* xrow = &xs[btl * XROW];
    const float* wcol = &ws[fg * 4];

    #pragma unroll 4
    for (int j = 0; j < 32; ++j) {
        float xr[16];
        #pragma unroll
        for (int q = 0; q < 4; ++q) {
            float4 v = *(const float4*)&xrow[j * 16 + q * 4];
            xr[q * 4 + 0] = v.x; xr[q * 4 + 1] = v.y;
            xr[q * 4 + 2] = v.z; xr[q * 4 + 3] = v.w;
        }
        #pragma unroll
        for (int i = 0; i < 3; ++i) {
            float4 w = *(const float4*)&wcol[(i * 32 + j) * 16];
            #pragma unroll
            for (int h = 0; h < 14; ++h) {
                float xv = xr[h + i];
                acc[h].x = fmaf(xv, w.x, acc[h].x);
                acc[h].y = fmaf(xv, w.y, acc[h].y);
                acc[h].z = fmaf(xv, w.z, acc[h].z);
                acc[h].w = fmaf(xv, w.w, acc[h].w);
            }
        }
    }

    const float4 b4 = *(const float4*)&bs[fg * 4];
    float* obase = out + bt * 224 + fg * 4;   // (14,16) per bt
    #pragma unroll
    for (int h = 0; h < 14; ++h) {
        float4 y;
        y.x = fmaxf((acc[h].x + b4.x) * sc + sh, 0.f);
        y.y = fmaxf((acc[h].y + b4.y) * sc + sh, 0.f);
        y.z = fmaxf((acc[h].z + b4.z) * sc + sh, 0.f);
        y.w = fmaxf((acc[h].w + b4.w) * sc + sh, 0.f);
        *(float4*)&obase[h * 16] = y;
    }
}

extern "C" void kernel_launch(void* const* d_in, const int* in_sizes, int n_in,
                              void* d_out, int out_size, void* d_ws, size_t ws_size,
                              hipStream_t stream) {
    const float* x     = (const float*)d_in[0];
    const float* kern  = (const float*)d_in[1];
    const float* bias  = (const float*)d_in[2];
    const float* gamma = (const float*)d_in[3];
    const float* beta  = (const float*)d_in[4];
    const float* mmean = (const float*)d_in[5];
    const float* mvar  = (const float*)d_in[6];
    float* out = (float*)d_out;

    const int n_bt = 64 * 4096;               // 262144
    const int blocks = n_bt / NBT;            // 8192
    tccnn_fused<<<blocks, 128, 0, stream>>>(x, kern, bias, gamma, beta,
                                            mmean, mvar, out);
}

// Round 4
// 151.597 us; speedup vs baseline: 1.5788x; 1.3122x over previous
//
#include <hip/hip_runtime.h>
#include <hip/hip_bf16.h>

// B=64, T=4096, Feat=32, Ch=16; kernel (3,32,1,16), Hp=14, Wp=1, F=16.
// out[bt,hp,f] = relu((conv + bias[f])*sc[t] + sh[t]),  t = bt % 4096
// conv[(bt,hp),f] = sum_{i<3,j<32} x[bt,j,hp+i] * k[i,j,f]
//   == GEMM  A(16x96) * Bw(96x16) per bt, K = i*32+j, A[m][k] = xT[m+i][j].
// R3: same as R2 but bf16 conversion via manual RNE bit ops (hip_bfloat162
// is not trivially copyable -> __builtin_bit_cast failed to compile).

typedef __attribute__((ext_vector_type(8))) short bf16x8;
typedef __attribute__((ext_vector_type(4))) float f32x4;

#define NBT 32               // bt tiles per block (256 thr = 4 waves * 8 bt)
#define XSTRIDE 40           // bf16 per xT row: 32 + 8 pad -> 80 B (16B-aligned rows)
#define XTILE (18 * XSTRIDE + 8)   // 728 bf16 per bt tile
#define WSTRIDE 104          // bf16 per BwT row: 96 + 8 pad (208 B, 16B-aligned)

__device__ __forceinline__ unsigned short f2bf(float f) {
    unsigned u = __builtin_bit_cast(unsigned, f);
    return (unsigned short)((u + 0x7fffu + ((u >> 16) & 1u)) >> 16);  // RNE
}
__device__ __forceinline__ unsigned pack2(float a, float b) {
    return (unsigned)f2bf(a) | ((unsigned)f2bf(b) << 16);
}

__global__ __launch_bounds__(256) void tccnn_mfma(
    const float* __restrict__ x,      // (B*T, 32, 16)
    const float* __restrict__ kern,   // (3,32,1,16) = 1536
    const float* __restrict__ bias,   // (16,)
    const float* __restrict__ gamma,  // (4096,)
    const float* __restrict__ beta,   // (4096,)
    const float* __restrict__ mmean,  // (4096,)
    const float* __restrict__ mvar,   // (4096,)
    float* __restrict__ out)          // (B*T, 14, 16)
{
    __shared__ __align__(16) unsigned short xs[NBT * XTILE];    // 46592 B
    __shared__ __align__(16) unsigned short wsh[16 * WSTRIDE];  // 3328 B

    const int tid = threadIdx.x;
    const long bt0 = (long)blockIdx.x * NBT;

    // ---- stage weights as BwT[f][k=i*32+j] bf16 ----
    for (int idx = tid; idx < 1536; idx += 256) {
        int ij = idx >> 4, f = idx & 15;          // kern[(ij)*16 + f]
        wsh[f * WSTRIDE + ij] = f2bf(kern[idx]);
    }

    // ---- stage x: per bt, xT[c][j] bf16 (rows 16,17 garbage -> only feed
    //      discarded hp=14,15). 4x4 transpose per unit; 1024 units, 4/thread.
    #pragma unroll
    for (int v = 0; v < 4; ++v) {
        int U = v * 256 + tid;
        int btl = U >> 5, u = U & 31;
        int cu = u & 3, ju = u >> 2;              // c0 = cu*4, j0 = ju*4
        const float4* src = (const float4*)(x + (bt0 + btl) * 512 + ju * 4 * 16 + cu * 4);
        float4 r0 = src[0];                        // x[j0+0][c0..c0+3]
        float4 r1 = src[4];                        // j stride = 16 floats
        float4 r2 = src[8];
        float4 r3 = src[12];
        unsigned short* dst = &xs[btl * XTILE + ju * 4];
        *(uint2*)&dst[(cu * 4 + 0) * XSTRIDE] =
            make_uint2(pack2(r0.x, r1.x), pack2(r2.x, r3.x));
        *(uint2*)&dst[(cu * 4 + 1) * XSTRIDE] =
            make_uint2(pack2(r0.y, r1.y), pack2(r2.y, r3.y));
        *(uint2*)&dst[(cu * 4 + 2) * XSTRIDE] =
            make_uint2(pack2(r0.z, r1.z), pack2(r2.z, r3.z));
        *(uint2*)&dst[(cu * 4 + 3) * XSTRIDE] =
            make_uint2(pack2(r0.w, r1.w), pack2(r2.w, r3.w));
    }
    __syncthreads();

    // ---- compute: each wave owns 8 bts; 3 MFMAs each ----
    const int lane = tid & 63;
    const int wv = tid >> 6;
    const int f = lane & 15;
    const int g = lane >> 4;                       // k-group / row-group

    bf16x8 bfr0 = *(const bf16x8*)&wsh[f * WSTRIDE + 0 * 32 + g * 8];
    bf16x8 bfr1 = *(const bf16x8*)&wsh[f * WSTRIDE + 1 * 32 + g * 8];
    bf16x8 bfr2 = *(const bf16x8*)&wsh[f * WSTRIDE + 2 * 32 + g * 8];
    const float bsf = bias[f];

    #pragma unroll 4
    for (int q = 0; q < 8; ++q) {
        const int btl = wv * 8 + q;
        const unsigned short* xt = &xs[btl * XTILE];
        // A-frags: lane reads xT[(l&15)+i][g*8 .. g*8+7]
        bf16x8 a0 = *(const bf16x8*)&xt[(f + 0) * XSTRIDE + g * 8];
        bf16x8 a1 = *(const bf16x8*)&xt[(f + 1) * XSTRIDE + g * 8];
        bf16x8 a2 = *(const bf16x8*)&xt[(f + 2) * XSTRIDE + g * 8];

        f32x4 acc = {0.f, 0.f, 0.f, 0.f};
        acc = __builtin_amdgcn_mfma_f32_16x16x32_bf16(a0, bfr0, acc, 0, 0, 0);
        acc = __builtin_amdgcn_mfma_f32_16x16x32_bf16(a1, bfr1, acc, 0, 0, 0);
        acc = __builtin_amdgcn_mfma_f32_16x16x32_bf16(a2, bfr2, acc, 0, 0, 0);

        const long bt = bt0 + btl;
        const int t = (int)(bt & 4095);
        const float sc = gamma[t] * rsqrtf(mvar[t] + 1e-3f);
        const float sh = beta[t] - mmean[t] * sc;
        float* ob = out + bt * 224 + f;            // C: row=(g*4+r)=hp, col=f
        #pragma unroll
        for (int r = 0; r < 4; ++r) {
            int row = g * 4 + r;
            if (row < 14)
                ob[row * 16] = fmaxf((acc[r] + bsf) * sc + sh, 0.f);
        }
    }
}

extern "C" void kernel_launch(void* const* d_in, const int* in_sizes, int n_in,
                              void* d_out, int out_size, void* d_ws, size_t ws_size,
                              hipStream_t stream) {
    const float* x     = (const float*)d_in[0];
    const float* kern  = (const float*)d_in[1];
    const float* bias  = (const float*)d_in[2];
    const float* gamma = (const float*)d_in[3];
    const float* beta  = (const float*)d_in[4];
    const float* mmean = (const float*)d_in[5];
    const float* mvar  = (const float*)d_in[6];
    float* out = (float*)d_out;

    const int n_bt = 64 * 4096;                    // 262144
    const int blocks = n_bt / NBT;                 // 8192
    tccnn_mfma<<<blocks, 256, 0, stream>>>(x, kern, bias, gamma, beta,
                                           mmean, mvar, out);
}

// Round 5
// 140.803 us; speedup vs baseline: 1.6999x; 1.0767x over previous
//
#include <hip/hip_runtime.h>
#include <hip/hip_bf16.h>

// B=64, T=4096, Feat=32, Ch=16; kernel (3,32,1,16), Hp=14, Wp=1, F=16.
// out[bt,hp,f] = relu((conv + bias[f])*sc[t] + sh[t]),  t = bt % 4096
// conv[(bt,hp),f] = sum_{i<3,j<32} x[bt,j,hp+i] * k[i,j,f]
// R5: swapped-operand MFMA: D[f][hp] = BwT(16x96) * xT^T ->
//   C layout col=lane&15=hp, row=f=g*4+reg -> lane holds out[hp][4g..4g+3]
//   = one float4 store per bt (was 4 scalar dwords). NBT=16 -> 26.6KB LDS
//   -> 6 blocks/CU = 24 waves/CU for stage/compute overlap.

typedef __attribute__((ext_vector_type(8))) short bf16x8;
typedef __attribute__((ext_vector_type(4))) float f32x4;

#define NBT 16               // bt tiles per block (4 waves * 4 bt)
#define XSTRIDE 40           // bf16 per xT row: 32 + 8 pad (80 B, 16B-aligned)
#define XTILE (18 * XSTRIDE + 8)   // 728 bf16 per bt tile (1456 B, 16B-aligned)
#define WSTRIDE 104          // bf16 per BwT row: 96 + 8 pad (208 B)

__device__ __forceinline__ unsigned short f2bf(float f) {
    unsigned u = __builtin_bit_cast(unsigned, f);
    return (unsigned short)((u + 0x7fffu + ((u >> 16) & 1u)) >> 16);  // RNE
}
__device__ __forceinline__ unsigned pack2(float a, float b) {
    return (unsigned)f2bf(a) | ((unsigned)f2bf(b) << 16);
}

__global__ __launch_bounds__(256) void tccnn_mfma(
    const float* __restrict__ x,      // (B*T, 32, 16)
    const float* __restrict__ kern,   // (3,32,1,16) = 1536
    const float* __restrict__ bias,   // (16,)
    const float* __restrict__ gamma,  // (4096,)
    const float* __restrict__ beta,   // (4096,)
    const float* __restrict__ mmean,  // (4096,)
    const float* __restrict__ mvar,   // (4096,)
    float* __restrict__ out)          // (B*T, 14, 16)
{
    __shared__ __align__(16) unsigned short xs[NBT * XTILE];    // 23296 B
    __shared__ __align__(16) unsigned short wsh[16 * WSTRIDE];  // 3328 B

    const int tid = threadIdx.x;
    const long bt0 = (long)blockIdx.x * NBT;

    // ---- stage weights as BwT[f][k=i*32+j] bf16 (1536 floats, 6/thread) ----
    #pragma unroll
    for (int v = 0; v < 6; ++v) {
        int idx = v * 256 + tid;
        int ij = idx >> 4, f = idx & 15;
        wsh[f * WSTRIDE + ij] = f2bf(kern[idx]);
    }

    // ---- stage x transposed: xT[c][j] bf16. Unit = 4c x 8j; 256 units,
    //      1/thread. 8x float4 loads -> 4x ds_write_b128. ----
    {
        int U = tid;
        int btl = U >> 4, u = U & 15;
        int cu = u & 3, ju = u >> 2;              // c0 = cu*4, j0 = ju*8
        const float4* src = (const float4*)(x + (bt0 + btl) * 512 + ju * 128 + cu * 4);
        float4 r0 = src[0],  r1 = src[4],  r2 = src[8],  r3 = src[12];
        float4 r4 = src[16], r5 = src[20], r6 = src[24], r7 = src[28];
        unsigned short* dst = &xs[btl * XTILE + ju * 8];
        *(uint4*)&dst[(cu * 4 + 0) * XSTRIDE] = make_uint4(
            pack2(r0.x, r1.x), pack2(r2.x, r3.x), pack2(r4.x, r5.x), pack2(r6.x, r7.x));
        *(uint4*)&dst[(cu * 4 + 1) * XSTRIDE] = make_uint4(
            pack2(r0.y, r1.y), pack2(r2.y, r3.y), pack2(r4.y, r5.y), pack2(r6.y, r7.y));
        *(uint4*)&dst[(cu * 4 + 2) * XSTRIDE] = make_uint4(
            pack2(r0.z, r1.z), pack2(r2.z, r3.z), pack2(r4.z, r5.z), pack2(r6.z, r7.z));
        *(uint4*)&dst[(cu * 4 + 3) * XSTRIDE] = make_uint4(
            pack2(r0.w, r1.w), pack2(r2.w, r3.w), pack2(r4.w, r5.w), pack2(r6.w, r7.w));
    }
    __syncthreads();

    // ---- compute: wave owns 4 bts; 3 MFMAs each (swapped operands) ----
    const int lane = tid & 63;
    const int wv = tid >> 6;
    const int hp = lane & 15;                      // C col = hp
    const int g = lane >> 4;                       // k-group; C rows f=g*4+r

    // A-operand (weights): lane provides BwT[f=lane&15][k=g*8+jj]
    bf16x8 bfr0 = *(const bf16x8*)&wsh[hp * WSTRIDE + 0 * 32 + g * 8];
    bf16x8 bfr1 = *(const bf16x8*)&wsh[hp * WSTRIDE + 1 * 32 + g * 8];
    bf16x8 bfr2 = *(const bf16x8*)&wsh[hp * WSTRIDE + 2 * 32 + g * 8];
    const float4 b4 = *(const float4*)&bias[g * 4]; // bias[f], f = g*4+r

    #pragma unroll
    for (int q = 0; q < 4; ++q) {
        const int btl = wv * 4 + q;
        const unsigned short* xt = &xs[btl * XTILE];
        // B-operand: lane provides xT[(lane&15)+i][k=g*8+jj]
        bf16x8 a0 = *(const bf16x8*)&xt[(hp + 0) * XSTRIDE + g * 8];
        bf16x8 a1 = *(const bf16x8*)&xt[(hp + 1) * XSTRIDE + g * 8];
        bf16x8 a2 = *(const bf16x8*)&xt[(hp + 2) * XSTRIDE + g * 8];

        f32x4 acc = {0.f, 0.f, 0.f, 0.f};
        acc = __builtin_amdgcn_mfma_f32_16x16x32_bf16(bfr0, a0, acc, 0, 0, 0);
        acc = __builtin_amdgcn_mfma_f32_16x16x32_bf16(bfr1, a1, acc, 0, 0, 0);
        acc = __builtin_amdgcn_mfma_f32_16x16x32_bf16(bfr2, a2, acc, 0, 0, 0);

        const long bt = bt0 + btl;
        const int t = (int)(bt & 4095);
        const float sc = gamma[t] * rsqrtf(mvar[t] + 1e-3f);
        const float sh = beta[t] - mmean[t] * sc;

        if (hp < 14) {
            float4 y;
            y.x = fmaxf((acc[0] + b4.x) * sc + sh, 0.f);
            y.y = fmaxf((acc[1] + b4.y) * sc + sh, 0.f);
            y.z = fmaxf((acc[2] + b4.z) * sc + sh, 0.f);
            y.w = fmaxf((acc[3] + b4.w) * sc + sh, 0.f);
            *(float4*)(out + bt * 224 + hp * 16 + g * 4) = y;
        }
    }
}

extern "C" void kernel_launch(void* const* d_in, const int* in_sizes, int n_in,
                              void* d_out, int out_size, void* d_ws, size_t ws_size,
                              hipStream_t stream) {
    const float* x     = (const float*)d_in[0];
    const float* kern  = (const float*)d_in[1];
    const float* bias  = (const float*)d_in[2];
    const float* gamma = (const float*)d_in[3];
    const float* beta  = (const float*)d_in[4];
    const float* mmean = (const float*)d_in[5];
    const float* mvar  = (const float*)d_in[6];
    float* out = (float*)d_out;

    const int n_bt = 64 * 4096;                    // 262144
    const int blocks = n_bt / NBT;                 // 16384
    tccnn_mfma<<<blocks, 256, 0, stream>>>(x, kern, bias, gamma, beta,
                                           mmean, mvar, out);
}